// Round 1
// baseline (1375.574 us; speedup 1.0000x reference)
//
#include <hip/hip_runtime.h>

#define BB 16
#define SS 512
#define DM 256
#define NH 8
#define DKK 32
#define DVV 32
#define NROW 32
#define TQ 8

// workspace layout in floats
#define OFF_QP   0
#define OFF_KT   2097152
#define OFF_VP   4194304
#define OFF_VP2  6291456
#define OFF_CTX  6553600
#define OFF_CTX2 8650752
#define OFF_FLAG 8912896

#define SCALE 0.17677669529663687f

// ---------------------------------------------------------------------------
// K0: detect how the bool mask was uploaded. OR-reduce first 64K words:
//   result <= 1            -> int32 (0/1 values)            flag=0
//   result == 0x3F800000   -> float32 (0.0/1.0)             flag=2
//   else (e.g. 0x01010101) -> uint8 packed bytes            flag=1
__global__ void detect_mask_kernel(const unsigned int* __restrict__ w, int n,
                                   int* __restrict__ flag) {
  __shared__ unsigned int sh[256];
  unsigned int a = 0;
  for (int i = threadIdx.x; i < n; i += 256) a |= w[i];
  sh[threadIdx.x] = a;
  __syncthreads();
  for (int s = 128; s > 0; s >>= 1) {
    if (threadIdx.x < s) sh[threadIdx.x] |= sh[threadIdx.x + s];
    __syncthreads();
  }
  if (threadIdx.x == 0) {
    unsigned int r = sh[0];
    *flag = (r <= 1u) ? 0 : ((r == 0x3F800000u) ? 2 : 1);
  }
}

// ---------------------------------------------------------------------------
// K1: projections. One block = 32 rows of (b,s). Thread t = output column.
//   Qp[b,s,c], Vp[b,s,c]  row-major
//   Kt[b, h, d, s]  (transposed per head, so score kernel reads coalesced)
//   Vp2[b,s,dv]
__global__ __launch_bounds__(256) void proj_kernel(
    const float* __restrict__ inQ, const float* __restrict__ inK,
    const float* __restrict__ inV,
    const float* __restrict__ Wq, const float* __restrict__ Wk,
    const float* __restrict__ Wv, const float* __restrict__ Wv2,
    float* __restrict__ Qp, float* __restrict__ Kt,
    float* __restrict__ Vp, float* __restrict__ Vp2) {
  __shared__ float xs[NROW][257];
  const int t = threadIdx.x;
  const int r0 = blockIdx.x * NROW;
  float acc[NROW];

  // ---- Q ----
  for (int e = t; e < NROW * DM; e += 256) {
    int r = e >> 8, i = e & 255;
    xs[r][i] = inQ[(r0 + r) * DM + i];
  }
  __syncthreads();
#pragma unroll
  for (int r = 0; r < NROW; r++) acc[r] = 0.f;
  for (int i = 0; i < DM; i++) {
    float w = Wq[i * 256 + t];
#pragma unroll
    for (int r = 0; r < NROW; r++) acc[r] += xs[r][i] * w;
  }
#pragma unroll
  for (int r = 0; r < NROW; r++) Qp[(r0 + r) * 256 + t] = acc[r];
  __syncthreads();

  // ---- K (store transposed per head: Kt[(b*256 + t)*512 + s]) ----
  for (int e = t; e < NROW * DM; e += 256) {
    int r = e >> 8, i = e & 255;
    xs[r][i] = inK[(r0 + r) * DM + i];
  }
  __syncthreads();
#pragma unroll
  for (int r = 0; r < NROW; r++) acc[r] = 0.f;
  for (int i = 0; i < DM; i++) {
    float w = Wk[i * 256 + t];
#pragma unroll
    for (int r = 0; r < NROW; r++) acc[r] += xs[r][i] * w;
  }
#pragma unroll
  for (int r = 0; r < NROW; r++) {
    int rg = r0 + r;
    int b = rg >> 9, sidx = rg & 511;
    Kt[(b * 256 + t) * 512 + sidx] = acc[r];
  }
  __syncthreads();

  // ---- V ----
  for (int e = t; e < NROW * DM; e += 256) {
    int r = e >> 8, i = e & 255;
    xs[r][i] = inV[(r0 + r) * DM + i];
  }
  __syncthreads();
#pragma unroll
  for (int r = 0; r < NROW; r++) acc[r] = 0.f;
  for (int i = 0; i < DM; i++) {
    float w = Wv[i * 256 + t];
#pragma unroll
    for (int r = 0; r < NROW; r++) acc[r] += xs[r][i] * w;
  }
#pragma unroll
  for (int r = 0; r < NROW; r++) Vp[(r0 + r) * 256 + t] = acc[r];

  // ---- V2 (reuse V rows in LDS): 32 cols, 8 row-groups of 4 ----
  {
    int c2 = t & 31, rr = t >> 5;
    float a4[4] = {0.f, 0.f, 0.f, 0.f};
    for (int i = 0; i < DM; i++) {
      float w2 = Wv2[i * 32 + c2];
#pragma unroll
      for (int j = 0; j < 4; j++) a4[j] += xs[rr + 8 * j][i] * w2;
    }
#pragma unroll
    for (int j = 0; j < 4; j++) Vp2[(r0 + rr + 8 * j) * 32 + c2] = a4[j];
  }
}

// ---------------------------------------------------------------------------
// K2: fused attention + gate. Block = 512 threads (8 waves), one wave per
// head, q-tile of 8 rows. Scores held in registers (8 q x 8 kgroups per lane).
__global__ __launch_bounds__(512) void attn_kernel(
    const float* __restrict__ Qp, const float* __restrict__ Kt,
    const float* __restrict__ Vp, const void* __restrict__ mask,
    const float* __restrict__ matrix,
    const float* __restrict__ fulng, const float* __restrict__ fulnb,
    const float* __restrict__ fuw1, const float* __restrict__ fub1,
    const float* __restrict__ fuw2, const float* __restrict__ fub2,
    float* __restrict__ ctx, float* __restrict__ mout,
    const int* __restrict__ flag) {
  __shared__ float Qs[TQ][DM];      // 8 KB
  __shared__ float P[NH][TQ][64];   // 16 KB  attn probs for one k-tile
  __shared__ float M1[TQ][64];      // 2 KB   matrix[b, q-tile, k-tile]
  __shared__ float G[64][9];        // gate outputs (padded stride 9)
  __shared__ float fup[85];

  const int tid = threadIdx.x;
  const int lane = tid & 63;
  const int h = tid >> 6;  // wave id == head
  const int b = blockIdx.x >> 6;
  const int q0 = (blockIdx.x & 63) * TQ;

  // stage Q rows + gate params
  for (int e = tid; e < TQ * DM; e += 512) {
    int q = e >> 8, i = e & 255;
    Qs[q][i] = Qp[((b << 9) + q0 + q) * 256 + i];
  }
  if (tid < 9) fup[tid] = fulng[tid];
  else if (tid < 18) fup[tid] = fulnb[tid - 9];
  else if (tid < 72) fup[tid] = fuw1[tid - 18];
  else if (tid < 78) fup[tid] = fub1[tid - 72];
  else if (tid < 84) fup[tid] = fuw2[tid - 78];
  else if (tid == 84) fup[tid] = fub2[0];
  const int flagv = *flag;
  __syncthreads();

  const int* mask_i = (const int*)mask;
  const unsigned char* mask_b = (const unsigned char*)mask;
  const float* mask_f = (const float*)mask;

  float s[TQ][8];  // scores: [q][kgroup], k = kg*64 + lane

  // ---- phase 1: scores + mask ----
  for (int kg = 0; kg < 8; kg++) {
    int kglob = kg * 64 + lane;
    float kc[DKK];
#pragma unroll
    for (int d = 0; d < DKK; d++)
      kc[d] = Kt[(b * 256 + h * 32 + d) * 512 + kglob];
#pragma unroll
    for (int q = 0; q < TQ; q++) {
      float a = 0.f;
#pragma unroll
      for (int d = 0; d < DKK; d++) a += Qs[q][h * 32 + d] * kc[d];
      a *= SCALE;
      int midx = ((b * 8 + h) * 512 + q0 + q) * 512 + kglob;
      bool m;
      if (flagv == 0) m = (mask_i[midx] != 0);
      else if (flagv == 1) m = (mask_b[midx] != 0);
      else m = (mask_f[midx] != 0.f);
      s[q][kg] = m ? -1e9f : a;
    }
  }

  // ---- softmax (per q row, across 8 regs x 64 lanes) ----
#pragma unroll
  for (int q = 0; q < TQ; q++) {
    float mx = s[q][0];
#pragma unroll
    for (int kg = 1; kg < 8; kg++) mx = fmaxf(mx, s[q][kg]);
#pragma unroll
    for (int off = 32; off > 0; off >>= 1) mx = fmaxf(mx, __shfl_xor(mx, off));
    float sum = 0.f;
#pragma unroll
    for (int kg = 0; kg < 8; kg++) {
      float e = __expf(s[q][kg] - mx);
      s[q][kg] = e;
      sum += e;
    }
#pragma unroll
    for (int off = 32; off > 0; off >>= 1) sum += __shfl_xor(sum, off);
    float inv = 1.f / sum;
#pragma unroll
    for (int kg = 0; kg < 8; kg++) s[q][kg] *= inv;
  }

  // ---- phase 2: per k-tile: gate (cross-head) + AV accumulate ----
  const int dv = lane & 31;
  const int qb = lane >> 5;  // 0 or 1
  float avacc[4] = {0.f, 0.f, 0.f, 0.f};  // q = qb + 2*j

  for (int kg = 0; kg < 8; kg++) {
    __syncthreads();
    // publish probs for this k-tile + stage matrix[b, q-tile, k-tile]
#pragma unroll
    for (int q = 0; q < TQ; q++) P[h][q][lane] = s[q][kg];
    {
      int gq = tid >> 6, gk = tid & 63;
      M1[gq][gk] = matrix[((b << 9) + q0 + gq) * 512 + kg * 64 + gk];
    }
    __syncthreads();

    // gate: one thread per (q,k) position
    {
      int gq = tid >> 6, gk = tid & 63;
      float v[9];
      v[0] = M1[gq][gk];
#pragma unroll
      for (int hh = 0; hh < NH; hh++) v[1 + hh] = P[hh][gq][gk];
      float mu = 0.f;
#pragma unroll
      for (int i = 0; i < 9; i++) mu += v[i];
      mu *= (1.f / 9.f);
      float var = 0.f;
#pragma unroll
      for (int i = 0; i < 9; i++) {
        float d = v[i] - mu;
        var += d * d;
      }
      var *= (1.f / 9.f);
      float inv = rsqrtf(var + 1e-5f);
      float y[9];
#pragma unroll
      for (int i = 0; i < 9; i++)
        y[i] = fup[i] * (v[i] - mu) * inv + fup[9 + i];
      float o = fup[84];
#pragma unroll
      for (int j = 0; j < 6; j++) {
        float z = fup[72 + j];
#pragma unroll
        for (int i = 0; i < 9; i++) z += y[i] * fup[18 + i * 6 + j];
        z = fmaxf(z, 0.f);
        o += z * fup[78 + j];
      }
      G[gk][gq] = 1.f / (1.f + __expf(-o));
    }

    // AV: wave h accumulates context for its head from LDS probs
    for (int kk = 0; kk < 64; kk++) {
      float vv = Vp[((b << 9) + kg * 64 + kk) * 256 + h * 32 + dv];
#pragma unroll
      for (int j = 0; j < 4; j++) avacc[j] += P[h][qb + 2 * j][kk] * vv;
    }
    __syncthreads();

    // matrix_out[b, k, q] = matrix[b, k, q] * g
    {
      int kk = tid >> 3, qq = tid & 7;
      int gi = ((b << 9) + kg * 64 + kk) * 512 + q0 + qq;
      mout[gi] = matrix[gi] * G[kk][qq];
    }
  }

  // write merged-head context: ctx[b, q, h*32+dv]
#pragma unroll
  for (int j = 0; j < 4; j++)
    ctx[((b << 9) + q0 + qb + 2 * j) * 256 + h * 32 + dv] = avacc[j];
}

// ---------------------------------------------------------------------------
// K3: context2[b,s,dv] = sum_k matrix[b,s,k] * Vp2[b,k,dv]
__global__ __launch_bounds__(256) void ctx2_kernel(
    const float* __restrict__ matrix, const float* __restrict__ Vp2,
    float* __restrict__ ctx2) {
  const int t = threadIdx.x;
  const int b = blockIdx.x >> 6;
  const int s0 = (blockIdx.x & 63) * 8;
  const int dv = t & 31, rr = t >> 5;
  const float* mrow = matrix + ((b << 9) + s0 + rr) * 512;
  const float* v2 = Vp2 + (b << 9) * 32 + dv;
  float a = 0.f;
  for (int k = 0; k < 512; k++) a += mrow[k] * v2[k * 32];
  ctx2[((b << 9) + s0 + rr) * 32 + dv] = a;
}

// ---------------------------------------------------------------------------
// K4: output = LN( [ctx | ctx2] @ W_fc )
__global__ __launch_bounds__(256) void final_kernel(
    const float* __restrict__ ctx, const float* __restrict__ ctx2,
    const float* __restrict__ Wfc, const float* __restrict__ lng,
    const float* __restrict__ lnb, float* __restrict__ out) {
  __shared__ float xs[32][288];
  __shared__ float red[32][4][2];
  const int t = threadIdx.x;
  const int lane = t & 63, wid = t >> 6;
  const int r0 = blockIdx.x * 32;

  for (int e = t; e < 32 * 288; e += 256) {
    int r = e / 288, i = e - r * 288;
    xs[r][i] = (i < 256) ? ctx[(r0 + r) * 256 + i]
                         : ctx2[(r0 + r) * 32 + (i - 256)];
  }
  __syncthreads();

  float acc[32];
#pragma unroll
  for (int r = 0; r < 32; r++) acc[r] = 0.f;
  for (int i = 0; i < 288; i++) {
    float w = Wfc[i * 256 + t];
#pragma unroll
    for (int r = 0; r < 32; r++) acc[r] += xs[r][i] * w;
  }

  // layernorm over the 256 columns (one per thread) of each row
#pragma unroll
  for (int r = 0; r < 32; r++) {
    float s1 = acc[r], s2 = acc[r] * acc[r];
#pragma unroll
    for (int off = 32; off > 0; off >>= 1) {
      s1 += __shfl_xor(s1, off);
      s2 += __shfl_xor(s2, off);
    }
    if (lane == 0) {
      red[r][wid][0] = s1;
      red[r][wid][1] = s2;
    }
  }
  __syncthreads();

  float gt = lng[t], bt = lnb[t];
#pragma unroll
  for (int r = 0; r < 32; r++) {
    float s1 = red[r][0][0] + red[r][1][0] + red[r][2][0] + red[r][3][0];
    float s2 = red[r][0][1] + red[r][1][1] + red[r][2][1] + red[r][3][1];
    float mu = s1 * (1.f / 256.f);
    float var = s2 * (1.f / 256.f) - mu * mu;
    float inv = rsqrtf(var + 1e-5f);
    out[(r0 + r) * 256 + t] = gt * (acc[r] - mu) * inv + bt;
  }
}

// ---------------------------------------------------------------------------
extern "C" void kernel_launch(void* const* d_in, const int* in_sizes, int n_in,
                              void* d_out, int out_size, void* d_ws,
                              size_t ws_size, hipStream_t stream) {
  const float* inQ = (const float*)d_in[0];
  const float* inK = (const float*)d_in[1];
  const float* inV = (const float*)d_in[2];
  const void* mask = d_in[3];
  const float* matrix = (const float*)d_in[4];
  const float* Wq = (const float*)d_in[5];
  const float* Wk = (const float*)d_in[6];
  const float* Wv = (const float*)d_in[7];
  const float* Wv2 = (const float*)d_in[8];
  const float* Wfc = (const float*)d_in[9];
  const float* lng = (const float*)d_in[10];
  const float* lnb = (const float*)d_in[11];
  const float* fulng = (const float*)d_in[12];
  const float* fulnb = (const float*)d_in[13];
  const float* fuw1 = (const float*)d_in[14];
  const float* fub1 = (const float*)d_in[15];
  const float* fuw2 = (const float*)d_in[16];
  const float* fub2 = (const float*)d_in[17];

  float* ws = (float*)d_ws;
  float* Qp = ws + OFF_QP;
  float* Kt = ws + OFF_KT;
  float* Vp = ws + OFF_VP;
  float* Vp2 = ws + OFF_VP2;
  float* ctx = ws + OFF_CTX;
  float* ctx2 = ws + OFF_CTX2;
  int* flag = (int*)(ws + OFF_FLAG);

  float* out = (float*)d_out;
  float* mout = out + BB * SS * DM;  // matrix_out after output

  detect_mask_kernel<<<1, 256, 0, stream>>>((const unsigned int*)mask, 65536,
                                            flag);
  proj_kernel<<<BB * SS / NROW, 256, 0, stream>>>(inQ, inK, inV, Wq, Wk, Wv,
                                                  Wv2, Qp, Kt, Vp, Vp2);
  attn_kernel<<<BB * (SS / TQ), 512, 0, stream>>>(
      Qp, Kt, Vp, mask, matrix, fulng, fulnb, fuw1, fub1, fuw2, fub2, ctx,
      mout, flag);
  ctx2_kernel<<<BB * (SS / 8), 256, 0, stream>>>(matrix, Vp2, ctx2);
  final_kernel<<<BB * SS / 32, 256, 0, stream>>>(ctx, ctx2, Wfc, lng, lnb,
                                                 out);
}

// Round 2
// 1195.563 us; speedup vs baseline: 1.1506x; 1.1506x over previous
//
#include <hip/hip_runtime.h>
#include <hip/hip_bf16.h>

#define BB 16
#define SS 512
#define DM 256
#define NH 8
#define DKK 32
#define DVV 32
#define TQ 8

// workspace layout in float units
#define OFF_QP   0
#define OFF_KT   2097152
#define OFF_VB   4194304   // bf16 V [b,s,c]: 2097152 elems = 1048576 floats
#define OFF_VP2  5242880
#define OFF_CTX  5505024
#define OFF_CTX2 7602176
#define OFF_G    7864320   // bf16 g [b,q,k]: 4194304 elems = 2097152 floats
#define OFF_FLAG 9961472

#define SCALE 0.17677669529663687f

// ---------------------------------------------------------------------------
// K0: OR-reduce first 64K words of the mask into *acc (acc pre-zeroed by
// hipMemsetAsync). Consumers classify: <=1 -> int32, ==0x3F800000 -> f32,
// else packed uint8.
__global__ void mask_or_kernel(const unsigned int* __restrict__ w,
                               unsigned int* __restrict__ acc) {
  __shared__ unsigned int sh[256];
  unsigned int a = 0;
  int base = blockIdx.x * 1024;
  for (int i = threadIdx.x; i < 1024; i += 256) a |= w[base + i];
  sh[threadIdx.x] = a;
  __syncthreads();
  for (int s = 128; s > 0; s >>= 1) {
    if (threadIdx.x < s) sh[threadIdx.x] |= sh[threadIdx.x + s];
    __syncthreads();
  }
  if (threadIdx.x == 0) atomicOr(acc, sh[0]);
}

// ---------------------------------------------------------------------------
// K1: projections. 512 threads: column c = tid&255, row-half hf = tid>>8.
// Qp[b,s,c] f32, Kt[b,c,s] f32, Vb[b,s,c] bf16, Vp2[b,s,dv] f32.
__global__ __launch_bounds__(512) void proj_kernel(
    const float* __restrict__ inQ, const float* __restrict__ inK,
    const float* __restrict__ inV,
    const float* __restrict__ Wq, const float* __restrict__ Wk,
    const float* __restrict__ Wv, const float* __restrict__ Wv2,
    float* __restrict__ Qp, float* __restrict__ Kt,
    __hip_bfloat16* __restrict__ Vb, float* __restrict__ Vp2) {
  __shared__ float xs[32][257];
  const int tid = threadIdx.x;
  const int c = tid & 255;
  const int hf = tid >> 8;
  const int rbase = hf * 16;
  const int r0 = blockIdx.x * 32;
  float acc[16];

  // ---- Q ----
  for (int e = tid; e < 32 * DM; e += 512) {
    int r = e >> 8, i = e & 255;
    xs[r][i] = inQ[(r0 + r) * DM + i];
  }
  __syncthreads();
#pragma unroll
  for (int r = 0; r < 16; r++) acc[r] = 0.f;
  for (int i = 0; i < DM; i++) {
    float w = Wq[i * 256 + c];
#pragma unroll
    for (int r = 0; r < 16; r++) acc[r] += xs[rbase + r][i] * w;
  }
#pragma unroll
  for (int r = 0; r < 16; r++) Qp[(r0 + rbase + r) * 256 + c] = acc[r];
  __syncthreads();

  // ---- K (store transposed per head: Kt[(b*256+c)*512 + s]) ----
  for (int e = tid; e < 32 * DM; e += 512) {
    int r = e >> 8, i = e & 255;
    xs[r][i] = inK[(r0 + r) * DM + i];
  }
  __syncthreads();
#pragma unroll
  for (int r = 0; r < 16; r++) acc[r] = 0.f;
  for (int i = 0; i < DM; i++) {
    float w = Wk[i * 256 + c];
#pragma unroll
    for (int r = 0; r < 16; r++) acc[r] += xs[rbase + r][i] * w;
  }
#pragma unroll
  for (int r = 0; r < 16; r++) {
    int rg = r0 + rbase + r;
    int b = rg >> 9, sidx = rg & 511;
    Kt[(b * 256 + c) * 512 + sidx] = acc[r];
  }
  __syncthreads();

  // ---- V (bf16 row-major out) ----
  for (int e = tid; e < 32 * DM; e += 512) {
    int r = e >> 8, i = e & 255;
    xs[r][i] = inV[(r0 + r) * DM + i];
  }
  __syncthreads();
#pragma unroll
  for (int r = 0; r < 16; r++) acc[r] = 0.f;
  for (int i = 0; i < DM; i++) {
    float w = Wv[i * 256 + c];
#pragma unroll
    for (int r = 0; r < 16; r++) acc[r] += xs[rbase + r][i] * w;
  }
#pragma unroll
  for (int r = 0; r < 16; r++)
    Vb[(r0 + rbase + r) * 256 + c] = __float2bfloat16(acc[r]);

  // ---- V2 (reuse V rows in LDS): 32 cols, 16 row-groups of 2 ----
  {
    int c2 = tid & 31, rr = tid >> 5;  // rr in 0..15
    float a2[2] = {0.f, 0.f};
    for (int i = 0; i < DM; i++) {
      float w2 = Wv2[i * 32 + c2];
#pragma unroll
      for (int j = 0; j < 2; j++) a2[j] += xs[rr + 16 * j][i] * w2;
    }
#pragma unroll
    for (int j = 0; j < 2; j++) Vp2[(r0 + rr + 16 * j) * 32 + c2] = a2[j];
  }
}

// ---------------------------------------------------------------------------
// K2: fused scores + softmax + gate + AV. 512 threads (8 waves = 8 heads),
// q-tile of 8. Scores in registers. Gate writes g (bf16, coalesced rows);
// AV from LDS-staged bf16 V tile. No mout writes here.
__global__ __launch_bounds__(512, 4) void attn_kernel(
    const float* __restrict__ Qp, const float* __restrict__ Kt,
    const __hip_bfloat16* __restrict__ Vb, const void* __restrict__ mask,
    const float* __restrict__ matrix,
    const float* __restrict__ fulng, const float* __restrict__ fulnb,
    const float* __restrict__ fuw1, const float* __restrict__ fub1,
    const float* __restrict__ fuw2, const float* __restrict__ fub2,
    float* __restrict__ ctx, __hip_bfloat16* __restrict__ gws,
    const unsigned int* __restrict__ orv) {
  __shared__ float Qs[TQ][DM];              // 8 KB
  __shared__ float P[NH][TQ][64];           // 16 KB
  __shared__ float M1[TQ][64];              // 2 KB
  __shared__ __hip_bfloat16 Vs[64][256];    // 32 KB
  __shared__ float fup[85];

  const int tid = threadIdx.x;
  const int lane = tid & 63;
  const int h = tid >> 6;
  const int b = blockIdx.x >> 6;
  const int q0 = (blockIdx.x & 63) * TQ;

  for (int e = tid; e < TQ * DM; e += 512) {
    int q = e >> 8, i = e & 255;
    Qs[q][i] = Qp[((b << 9) + q0 + q) * 256 + i];
  }
  if (tid < 9) fup[tid] = fulng[tid];
  else if (tid < 18) fup[tid] = fulnb[tid - 9];
  else if (tid < 72) fup[tid] = fuw1[tid - 18];
  else if (tid < 78) fup[tid] = fub1[tid - 72];
  else if (tid < 84) fup[tid] = fuw2[tid - 78];
  else if (tid == 84) fup[tid] = fub2[0];
  const unsigned int rawor = *orv;
  const int flagv = (rawor <= 1u) ? 0 : ((rawor == 0x3F800000u) ? 2 : 1);
  __syncthreads();

  const int* mask_i = (const int*)mask;
  const unsigned char* mask_b = (const unsigned char*)mask;
  const float* mask_f = (const float*)mask;

  float s[TQ][8];

  // ---- phase 1: scores + mask ----
  for (int kg = 0; kg < 8; kg++) {
    int kglob = kg * 64 + lane;
    float kc[DKK];
#pragma unroll
    for (int d = 0; d < DKK; d++)
      kc[d] = Kt[(b * 256 + h * 32 + d) * 512 + kglob];
#pragma unroll
    for (int q = 0; q < TQ; q++) {
      float a = 0.f;
#pragma unroll
      for (int d = 0; d < DKK; d++) a += Qs[q][h * 32 + d] * kc[d];
      a *= SCALE;
      int midx = ((b * 8 + h) * 512 + q0 + q) * 512 + kglob;
      bool m;
      if (flagv == 0) m = (mask_i[midx] != 0);
      else if (flagv == 1) m = (mask_b[midx] != 0);
      else m = (mask_f[midx] != 0.f);
      s[q][kg] = m ? -1e9f : a;
    }
  }

  // ---- softmax ----
#pragma unroll
  for (int q = 0; q < TQ; q++) {
    float mx = s[q][0];
#pragma unroll
    for (int kg = 1; kg < 8; kg++) mx = fmaxf(mx, s[q][kg]);
#pragma unroll
    for (int off = 32; off > 0; off >>= 1) mx = fmaxf(mx, __shfl_xor(mx, off));
    float sum = 0.f;
#pragma unroll
    for (int kg = 0; kg < 8; kg++) {
      float e = __expf(s[q][kg] - mx);
      s[q][kg] = e;
      sum += e;
    }
#pragma unroll
    for (int off = 32; off > 0; off >>= 1) sum += __shfl_xor(sum, off);
    float inv = 1.f / sum;
#pragma unroll
    for (int kg = 0; kg < 8; kg++) s[q][kg] *= inv;
  }

  // ---- phase 2: per k-tile: gate + AV ----
  const int dv = lane & 31;
  const int qb = lane >> 5;
  float avacc[4] = {0.f, 0.f, 0.f, 0.f};

  for (int kg = 0; kg < 8; kg++) {
    __syncthreads();
#pragma unroll
    for (int q = 0; q < TQ; q++) P[h][q][lane] = s[q][kg];
    {
      int gq = tid >> 6, gk = tid & 63;
      M1[gq][gk] = matrix[((b << 9) + q0 + gq) * 512 + kg * 64 + gk];
    }
    // stage V tile [64 k][256 c] bf16, vectorized copy
#pragma unroll
    for (int it = 0; it < 4; it++) {
      int idx = tid + it * 512;
      int kk = idx >> 5, c8 = (idx & 31) * 8;
      *(uint4*)&Vs[kk][c8] =
          *(const uint4*)&Vb[((b << 9) + kg * 64 + kk) * 256 + c8];
    }
    __syncthreads();

    // gate: one thread per (q,k) position; write g (coalesced rows of k)
    {
      int gq = tid >> 6, gk = tid & 63;
      float v[9];
      v[0] = M1[gq][gk];
#pragma unroll
      for (int hh = 0; hh < NH; hh++) v[1 + hh] = P[hh][gq][gk];
      float mu = 0.f;
#pragma unroll
      for (int i = 0; i < 9; i++) mu += v[i];
      mu *= (1.f / 9.f);
      float var = 0.f;
#pragma unroll
      for (int i = 0; i < 9; i++) {
        float d = v[i] - mu;
        var += d * d;
      }
      var *= (1.f / 9.f);
      float inv = rsqrtf(var + 1e-5f);
      float y[9];
#pragma unroll
      for (int i = 0; i < 9; i++)
        y[i] = fup[i] * (v[i] - mu) * inv + fup[9 + i];
      float o = fup[84];
#pragma unroll
      for (int j = 0; j < 6; j++) {
        float z = fup[72 + j];
#pragma unroll
        for (int i = 0; i < 9; i++) z += y[i] * fup[18 + i * 6 + j];
        z = fmaxf(z, 0.f);
        o += z * fup[78 + j];
      }
      float gv = 1.f / (1.f + __expf(-o));
      gws[((b << 9) + q0 + gq) * 512 + kg * 64 + gk] = __float2bfloat16(gv);
    }

    // AV from LDS: wave h, lane = (qhalf, dv)
    for (int kk = 0; kk < 64; kk++) {
      float vv = __bfloat162float(Vs[kk][h * 32 + dv]);
#pragma unroll
      for (int j = 0; j < 4; j++) avacc[j] += P[h][qb + 2 * j][kk] * vv;
    }
  }

#pragma unroll
  for (int j = 0; j < 4; j++)
    ctx[((b << 9) + q0 + qb + 2 * j) * 256 + h * 32 + dv] = avacc[j];
}

// ---------------------------------------------------------------------------
// K3: mout[b,j,i] = matrix[b,j,i] * g[b,i,j]. 64x64 tiles, LDS transpose.
__global__ __launch_bounds__(256) void mout_kernel(
    const float* __restrict__ matrix, const __hip_bfloat16* __restrict__ g,
    float* __restrict__ mout) {
  __shared__ float Gs[64][65];
  const int tid = threadIdx.x;
  const int b = blockIdx.x >> 6;
  const int j0 = ((blockIdx.x >> 3) & 7) * 64;
  const int i0 = (blockIdx.x & 7) * 64;

  // load g tile: rows i (64) x cols j (64), straight into Gs[i][j]
  {
    int r = tid >> 2, c0 = (tid & 3) * 16;
    const __hip_bfloat16* gp = g + (((b << 9) + i0 + r) << 9) + j0 + c0;
    ushort us[16];
    *(uint4*)(us) = *(const uint4*)(gp);
    *(uint4*)(us + 8) = *(const uint4*)(gp + 8);
#pragma unroll
    for (int k = 0; k < 16; k++) {
      __hip_bfloat16 hv = *(__hip_bfloat16*)&us[k];
      Gs[r][c0 + k] = __bfloat162float(hv);
    }
  }
  __syncthreads();

  // multiply: thread -> mout row jj, 16 cols of i (read Gs transposed)
  {
    int jj = tid >> 2, ic = (tid & 3) * 16;
    const float* mp = matrix + (((b << 9) + j0 + jj) << 9) + i0 + ic;
    float* op = mout + (((b << 9) + j0 + jj) << 9) + i0 + ic;
#pragma unroll
    for (int v4 = 0; v4 < 4; v4++) {
      float4 m = *(const float4*)(mp + v4 * 4);
      float4 o;
      o.x = m.x * Gs[ic + v4 * 4 + 0][jj];
      o.y = m.y * Gs[ic + v4 * 4 + 1][jj];
      o.z = m.z * Gs[ic + v4 * 4 + 2][jj];
      o.w = m.w * Gs[ic + v4 * 4 + 3][jj];
      *(float4*)(op + v4 * 4) = o;
    }
  }
}

// ---------------------------------------------------------------------------
// K4: context2[b,s,dv] = sum_k matrix[b,s,k] * Vp2[b,k,dv]
__global__ __launch_bounds__(256) void ctx2_kernel(
    const float* __restrict__ matrix, const float* __restrict__ Vp2,
    float* __restrict__ ctx2) {
  const int t = threadIdx.x;
  const int b = blockIdx.x >> 6;
  const int s0 = (blockIdx.x & 63) * 8;
  const int dv = t & 31, rr = t >> 5;
  const float* mrow = matrix + ((b << 9) + s0 + rr) * 512;
  const float* v2 = Vp2 + (b << 9) * 32 + dv;
  float a = 0.f;
  for (int k = 0; k < 512; k++) a += mrow[k] * v2[k * 32];
  ctx2[((b << 9) + s0 + rr) * 32 + dv] = a;
}

// ---------------------------------------------------------------------------
// K5: output = LN( [ctx | ctx2] @ W_fc ). 512 threads: col c, row-half hf.
__global__ __launch_bounds__(512) void final_kernel(
    const float* __restrict__ ctx, const float* __restrict__ ctx2,
    const float* __restrict__ Wfc, const float* __restrict__ lng,
    const float* __restrict__ lnb, float* __restrict__ out) {
  __shared__ float xs[32][289];
  __shared__ float red[32][4][2];
  const int tid = threadIdx.x;
  const int c = tid & 255;
  const int hf = tid >> 8;
  const int rbase = hf * 16;
  const int lane = tid & 63, wid = (tid >> 6) & 3;
  const int r0 = blockIdx.x * 32;

  for (int e = tid; e < 32 * 288; e += 512) {
    int r = e / 288, i = e - r * 288;
    xs[r][i] = (i < 256) ? ctx[(r0 + r) * 256 + i]
                         : ctx2[(r0 + r) * 32 + (i - 256)];
  }
  __syncthreads();

  float acc[16];
#pragma unroll
  for (int r = 0; r < 16; r++) acc[r] = 0.f;
  for (int i = 0; i < 288; i++) {
    float w = Wfc[i * 256 + c];
#pragma unroll
    for (int r = 0; r < 16; r++) acc[r] += xs[rbase + r][i] * w;
  }

#pragma unroll
  for (int r = 0; r < 16; r++) {
    float s1 = acc[r], s2 = acc[r] * acc[r];
#pragma unroll
    for (int off = 32; off > 0; off >>= 1) {
      s1 += __shfl_xor(s1, off);
      s2 += __shfl_xor(s2, off);
    }
    if (lane == 0) {
      red[rbase + r][wid][0] = s1;
      red[rbase + r][wid][1] = s2;
    }
  }
  __syncthreads();

  float gt = lng[c], bt = lnb[c];
#pragma unroll
  for (int r = 0; r < 16; r++) {
    int row = rbase + r;
    float s1 = red[row][0][0] + red[row][1][0] + red[row][2][0] + red[row][3][0];
    float s2 = red[row][0][1] + red[row][1][1] + red[row][2][1] + red[row][3][1];
    float mu = s1 * (1.f / 256.f);
    float var = s2 * (1.f / 256.f) - mu * mu;
    float inv = rsqrtf(var + 1e-5f);
    out[(r0 + row) * 256 + c] = gt * (acc[r] - mu) * inv + bt;
  }
}

// ---------------------------------------------------------------------------
extern "C" void kernel_launch(void* const* d_in, const int* in_sizes, int n_in,
                              void* d_out, int out_size, void* d_ws,
                              size_t ws_size, hipStream_t stream) {
  const float* inQ = (const float*)d_in[0];
  const float* inK = (const float*)d_in[1];
  const float* inV = (const float*)d_in[2];
  const void* mask = d_in[3];
  const float* matrix = (const float*)d_in[4];
  const float* Wq = (const float*)d_in[5];
  const float* Wk = (const float*)d_in[6];
  const float* Wv = (const float*)d_in[7];
  const float* Wv2 = (const float*)d_in[8];
  const float* Wfc = (const float*)d_in[9];
  const float* lng = (const float*)d_in[10];
  const float* lnb = (const float*)d_in[11];
  const float* fulng = (const float*)d_in[12];
  const float* fulnb = (const float*)d_in[13];
  const float* fuw1 = (const float*)d_in[14];
  const float* fub1 = (const float*)d_in[15];
  const float* fuw2 = (const float*)d_in[16];
  const float* fub2 = (const float*)d_in[17];

  float* ws = (float*)d_ws;
  float* Qp = ws + OFF_QP;
  float* Kt = ws + OFF_KT;
  __hip_bfloat16* Vb = (__hip_bfloat16*)(ws + OFF_VB);
  float* Vp2 = ws + OFF_VP2;
  float* ctx = ws + OFF_CTX;
  float* ctx2 = ws + OFF_CTX2;
  __hip_bfloat16* gws = (__hip_bfloat16*)(ws + OFF_G);
  unsigned int* flag = (unsigned int*)(ws + OFF_FLAG);

  float* out = (float*)d_out;
  float* mout = out + BB * SS * DM;

  hipMemsetAsync(flag, 0, 4, stream);
  mask_or_kernel<<<64, 256, 0, stream>>>((const unsigned int*)mask, flag);
  proj_kernel<<<BB * SS / 32, 512, 0, stream>>>(inQ, inK, inV, Wq, Wk, Wv,
                                                Wv2, Qp, Kt, Vb, Vp2);
  attn_kernel<<<BB * (SS / TQ), 512, 0, stream>>>(
      Qp, Kt, Vb, mask, matrix, fulng, fulnb, fuw1, fub1, fuw2, fub2, ctx,
      gws, flag);
  mout_kernel<<<BB * 64, 256, 0, stream>>>(matrix, gws, mout);
  ctx2_kernel<<<BB * (SS / 8), 256, 0, stream>>>(matrix, Vp2, ctx2);
  final_kernel<<<BB * SS / 32, 512, 0, stream>>>(ctx, ctx2, Wfc, lng, lnb,
                                                 out);
}

// Round 3
// 928.228 us; speedup vs baseline: 1.4819x; 1.2880x over previous
//
#include <hip/hip_runtime.h>
#include <hip/hip_bf16.h>

#define BB 16
#define SS 512
#define DM 256
#define NH 8
#define DKK 32
#define DVV 32
#define TQ 8

// workspace layout in float units
#define OFF_QP   0
#define OFF_KT   2097152
#define OFF_VB   4194304   // bf16 V [b,s,c]: 2097152 elems = 1048576 floats
#define OFF_VP2  5242880
#define OFF_CTX  5505024
#define OFF_CTX2 7602176
#define OFF_G    7864320   // bf16 g [b,q,k]: 4194304 elems = 2097152 floats
#define OFF_FLAG 9961472

#define SCALE 0.17677669529663687f

// ---------------------------------------------------------------------------
// K0: OR-reduce first 64K words of the mask into *acc (acc pre-zeroed).
__global__ void mask_or_kernel(const unsigned int* __restrict__ w,
                               unsigned int* __restrict__ acc) {
  __shared__ unsigned int sh[256];
  unsigned int a = 0;
  int base = blockIdx.x * 1024;
  for (int i = threadIdx.x; i < 1024; i += 256) a |= w[base + i];
  sh[threadIdx.x] = a;
  __syncthreads();
  for (int s = 128; s > 0; s >>= 1) {
    if (threadIdx.x < s) sh[threadIdx.x] |= sh[threadIdx.x + s];
    __syncthreads();
  }
  if (threadIdx.x == 0) atomicOr(acc, sh[0]);
}

// ---------------------------------------------------------------------------
// K1: projections. 512 threads: c = tid&255, row-half hf = tid>>8 (8 rows
// each), 16 rows per block -> grid 512 (2 blocks/CU).
__global__ __launch_bounds__(512) void proj_kernel(
    const float* __restrict__ inQ, const float* __restrict__ inK,
    const float* __restrict__ inV,
    const float* __restrict__ Wq, const float* __restrict__ Wk,
    const float* __restrict__ Wv, const float* __restrict__ Wv2,
    float* __restrict__ Qp, float* __restrict__ Kt,
    __hip_bfloat16* __restrict__ Vb, float* __restrict__ Vp2) {
  __shared__ float xs[16][257];
  const int tid = threadIdx.x;
  const int c = tid & 255;
  const int hf = tid >> 8;
  const int rbase = hf * 8;
  const int r0 = blockIdx.x * 16;
  float acc[8];

  // ---- Q ----
  for (int e = tid; e < 16 * DM; e += 512) {
    int r = e >> 8, i = e & 255;
    xs[r][i] = inQ[(r0 + r) * DM + i];
  }
  __syncthreads();
#pragma unroll
  for (int r = 0; r < 8; r++) acc[r] = 0.f;
  for (int i = 0; i < DM; i++) {
    float w = Wq[i * 256 + c];
#pragma unroll
    for (int r = 0; r < 8; r++) acc[r] += xs[rbase + r][i] * w;
  }
#pragma unroll
  for (int r = 0; r < 8; r++) Qp[(r0 + rbase + r) * 256 + c] = acc[r];
  __syncthreads();

  // ---- K (store transposed per head: Kt[(b*256+c)*512 + s]) ----
  for (int e = tid; e < 16 * DM; e += 512) {
    int r = e >> 8, i = e & 255;
    xs[r][i] = inK[(r0 + r) * DM + i];
  }
  __syncthreads();
#pragma unroll
  for (int r = 0; r < 8; r++) acc[r] = 0.f;
  for (int i = 0; i < DM; i++) {
    float w = Wk[i * 256 + c];
#pragma unroll
    for (int r = 0; r < 8; r++) acc[r] += xs[rbase + r][i] * w;
  }
#pragma unroll
  for (int r = 0; r < 8; r++) {
    int rg = r0 + rbase + r;
    int b = rg >> 9, sidx = rg & 511;
    Kt[(b * 256 + c) * 512 + sidx] = acc[r];
  }
  __syncthreads();

  // ---- V (bf16 row-major out) ----
  for (int e = tid; e < 16 * DM; e += 512) {
    int r = e >> 8, i = e & 255;
    xs[r][i] = inV[(r0 + r) * DM + i];
  }
  __syncthreads();
#pragma unroll
  for (int r = 0; r < 8; r++) acc[r] = 0.f;
  for (int i = 0; i < DM; i++) {
    float w = Wv[i * 256 + c];
#pragma unroll
    for (int r = 0; r < 8; r++) acc[r] += xs[rbase + r][i] * w;
  }
#pragma unroll
  for (int r = 0; r < 8; r++)
    Vb[(r0 + rbase + r) * 256 + c] = __float2bfloat16(acc[r]);

  // ---- V2 (reuse V rows in LDS): one (row, col) per thread ----
  {
    int c2 = tid & 31, rr = tid >> 5;  // rr 0..15
    float a = 0.f;
    for (int i = 0; i < DM; i++) a += xs[rr][i] * Wv2[i * 32 + c2];
    Vp2[(r0 + rr) * 32 + c2] = a;
  }
}

// ---------------------------------------------------------------------------
// K2: fused scores + softmax + gate + AV. 512 threads (8 waves = 8 heads),
// q-tile of 8. XCD-swizzled so each XCD sees only 2 batches (L2 reuse of
// Kt/Vb). NOTE: no min-wave launch bound — forcing 4 waves/EU caps VGPR at
// 64 and spills the 64-float score state to scratch (round-2 regression).
__global__ __launch_bounds__(512) void attn_kernel(
    const float* __restrict__ Qp, const float* __restrict__ Kt,
    const __hip_bfloat16* __restrict__ Vb, const void* __restrict__ mask,
    const float* __restrict__ matrix,
    const float* __restrict__ fulng, const float* __restrict__ fulnb,
    const float* __restrict__ fuw1, const float* __restrict__ fub1,
    const float* __restrict__ fuw2, const float* __restrict__ fub2,
    float* __restrict__ ctx, __hip_bfloat16* __restrict__ gws,
    const unsigned int* __restrict__ orv) {
  __shared__ float Qs[TQ][DM];              // 8 KB
  __shared__ float P[NH][TQ][64];           // 16 KB
  __shared__ float M1[TQ][64];              // 2 KB
  __shared__ __hip_bfloat16 Vs[64][256];    // 32 KB
  __shared__ float fup[85];

  const int tid = threadIdx.x;
  const int lane = tid & 63;
  const int h = tid >> 6;
  // XCD-aware swizzle: XCD = blockIdx % 8 (heuristic); give each XCD 2 b's.
  const int slot = blockIdx.x >> 3;
  const int b = ((blockIdx.x & 7) << 1) | (slot >> 6);
  const int q0 = (slot & 63) * TQ;

  for (int e = tid; e < TQ * DM; e += 512) {
    int q = e >> 8, i = e & 255;
    Qs[q][i] = Qp[((b << 9) + q0 + q) * 256 + i];
  }
  if (tid < 9) fup[tid] = fulng[tid];
  else if (tid < 18) fup[tid] = fulnb[tid - 9];
  else if (tid < 72) fup[tid] = fuw1[tid - 18];
  else if (tid < 78) fup[tid] = fub1[tid - 72];
  else if (tid < 84) fup[tid] = fuw2[tid - 78];
  else if (tid == 84) fup[tid] = fub2[0];
  const unsigned int rawor = *orv;
  const int flagv = (rawor <= 1u) ? 0 : ((rawor == 0x3F800000u) ? 2 : 1);
  __syncthreads();

  const int* mask_i = (const int*)mask;
  const unsigned char* mask_b = (const unsigned char*)mask;
  const float* mask_f = (const float*)mask;

  float s[TQ][8];

  // ---- phase 1: scores + mask ----
  for (int kg = 0; kg < 8; kg++) {
    int kglob = kg * 64 + lane;
    float kc[DKK];
#pragma unroll
    for (int d = 0; d < DKK; d++)
      kc[d] = Kt[(b * 256 + h * 32 + d) * 512 + kglob];
#pragma unroll
    for (int q = 0; q < TQ; q++) {
      float a = 0.f;
#pragma unroll
      for (int d = 0; d < DKK; d++) a += Qs[q][h * 32 + d] * kc[d];
      a *= SCALE;
      int midx = ((b * 8 + h) * 512 + q0 + q) * 512 + kglob;
      bool m;
      if (flagv == 0) m = (mask_i[midx] != 0);
      else if (flagv == 1) m = (mask_b[midx] != 0);
      else m = (mask_f[midx] != 0.f);
      s[q][kg] = m ? -1e9f : a;
    }
  }

  // ---- softmax ----
#pragma unroll
  for (int q = 0; q < TQ; q++) {
    float mx = s[q][0];
#pragma unroll
    for (int kg = 1; kg < 8; kg++) mx = fmaxf(mx, s[q][kg]);
#pragma unroll
    for (int off = 32; off > 0; off >>= 1) mx = fmaxf(mx, __shfl_xor(mx, off));
    float sum = 0.f;
#pragma unroll
    for (int kg = 0; kg < 8; kg++) {
      float e = __expf(s[q][kg] - mx);
      s[q][kg] = e;
      sum += e;
    }
#pragma unroll
    for (int off = 32; off > 0; off >>= 1) sum += __shfl_xor(sum, off);
    float inv = 1.f / sum;
#pragma unroll
    for (int kg = 0; kg < 8; kg++) s[q][kg] *= inv;
  }

  // ---- phase 2: per k-tile: gate + AV ----
  const int dv = lane & 31;
  const int qb = lane >> 5;
  float avacc[4] = {0.f, 0.f, 0.f, 0.f};

  for (int kg = 0; kg < 8; kg++) {
    __syncthreads();
#pragma unroll
    for (int q = 0; q < TQ; q++) P[h][q][lane] = s[q][kg];
    {
      int gq = tid >> 6, gk = tid & 63;
      M1[gq][gk] = matrix[((b << 9) + q0 + gq) * 512 + kg * 64 + gk];
    }
#pragma unroll
    for (int it = 0; it < 4; it++) {
      int idx = tid + it * 512;
      int kk = idx >> 5, c8 = (idx & 31) * 8;
      *(uint4*)&Vs[kk][c8] =
          *(const uint4*)&Vb[((b << 9) + kg * 64 + kk) * 256 + c8];
    }
    __syncthreads();

    // gate
    {
      int gq = tid >> 6, gk = tid & 63;
      float v[9];
      v[0] = M1[gq][gk];
#pragma unroll
      for (int hh = 0; hh < NH; hh++) v[1 + hh] = P[hh][gq][gk];
      float mu = 0.f;
#pragma unroll
      for (int i = 0; i < 9; i++) mu += v[i];
      mu *= (1.f / 9.f);
      float var = 0.f;
#pragma unroll
      for (int i = 0; i < 9; i++) {
        float d = v[i] - mu;
        var += d * d;
      }
      var *= (1.f / 9.f);
      float inv = rsqrtf(var + 1e-5f);
      float y[9];
#pragma unroll
      for (int i = 0; i < 9; i++)
        y[i] = fup[i] * (v[i] - mu) * inv + fup[9 + i];
      float o = fup[84];
#pragma unroll
      for (int j = 0; j < 6; j++) {
        float z = fup[72 + j];
#pragma unroll
        for (int i = 0; i < 9; i++) z += y[i] * fup[18 + i * 6 + j];
        z = fmaxf(z, 0.f);
        o += z * fup[78 + j];
      }
      float gv = 1.f / (1.f + __expf(-o));
      gws[((b << 9) + q0 + gq) * 512 + kg * 64 + gk] = __float2bfloat16(gv);
    }

    // AV from LDS
    for (int kk = 0; kk < 64; kk++) {
      float vv = __bfloat162float(Vs[kk][h * 32 + dv]);
#pragma unroll
      for (int j = 0; j < 4; j++) avacc[j] += P[h][qb + 2 * j][kk] * vv;
    }
  }

#pragma unroll
  for (int j = 0; j < 4; j++)
    ctx[((b << 9) + q0 + qb + 2 * j) * 256 + h * 32 + dv] = avacc[j];
}

// ---------------------------------------------------------------------------
// K3: mout[b,j,i] = matrix[b,j,i] * g[b,i,j]. 64x64 tiles, LDS transpose.
__global__ __launch_bounds__(256) void mout_kernel(
    const float* __restrict__ matrix, const __hip_bfloat16* __restrict__ g,
    float* __restrict__ mout) {
  __shared__ float Gs[64][65];
  const int tid = threadIdx.x;
  const int b = blockIdx.x >> 6;
  const int j0 = ((blockIdx.x >> 3) & 7) * 64;
  const int i0 = (blockIdx.x & 7) * 64;

  {
    int r = tid >> 2, c0 = (tid & 3) * 16;
    const __hip_bfloat16* gp = g + (((b << 9) + i0 + r) << 9) + j0 + c0;
    ushort us[16];
    *(uint4*)(us) = *(const uint4*)(gp);
    *(uint4*)(us + 8) = *(const uint4*)(gp + 8);
#pragma unroll
    for (int k = 0; k < 16; k++) {
      __hip_bfloat16 hv = *(__hip_bfloat16*)&us[k];
      Gs[r][c0 + k] = __bfloat162float(hv);
    }
  }
  __syncthreads();

  {
    int jj = tid >> 2, ic = (tid & 3) * 16;
    const float* mp = matrix + (((b << 9) + j0 + jj) << 9) + i0 + ic;
    float* op = mout + (((b << 9) + j0 + jj) << 9) + i0 + ic;
#pragma unroll
    for (int v4 = 0; v4 < 4; v4++) {
      float4 m = *(const float4*)(mp + v4 * 4);
      float4 o;
      o.x = m.x * Gs[ic + v4 * 4 + 0][jj];
      o.y = m.y * Gs[ic + v4 * 4 + 1][jj];
      o.z = m.z * Gs[ic + v4 * 4 + 2][jj];
      o.w = m.w * Gs[ic + v4 * 4 + 3][jj];
      *(float4*)(op + v4 * 4) = o;
    }
  }
}

// ---------------------------------------------------------------------------
// K4: context2[b,s,dv] = sum_k matrix[b,s,k] * Vp2[b,k,dv]. LDS-tiled:
// 16 s-rows per block, k in 4 chunks of 128. Grid 512.
__global__ __launch_bounds__(256) void ctx2_kernel(
    const float* __restrict__ matrix, const float* __restrict__ Vp2,
    float* __restrict__ ctx2) {
  __shared__ float Ms[16][128];
  __shared__ float Vs2[128][32];
  const int t = threadIdx.x;
  const int b = blockIdx.x >> 5;
  const int s0 = (blockIdx.x & 31) * 16;
  const int dv = t & 31, rg = t >> 5;  // rg 0..7
  float acc0 = 0.f, acc1 = 0.f;
  for (int kc = 0; kc < 4; kc++) {
    __syncthreads();
#pragma unroll
    for (int it = 0; it < 8; it++) {
      int idx = t + it * 256;
      int r = idx >> 7, cc = idx & 127;
      Ms[r][cc] = matrix[((b << 9) + s0 + r) * 512 + kc * 128 + cc];
    }
#pragma unroll
    for (int it = 0; it < 4; it++) {
      int idx = t + it * 256;
      int k = idx >> 3, c4 = (idx & 7) * 4;
      *(float4*)&Vs2[k][c4] =
          *(const float4*)&Vp2[((b << 9) + kc * 128 + k) * 32 + c4];
    }
    __syncthreads();
    for (int k = 0; k < 128; k++) {
      float v = Vs2[k][dv];
      acc0 += Ms[rg][k] * v;
      acc1 += Ms[rg + 8][k] * v;
    }
  }
  ctx2[((b << 9) + s0 + rg) * 32 + dv] = acc0;
  ctx2[((b << 9) + s0 + rg + 8) * 32 + dv] = acc1;
}

// ---------------------------------------------------------------------------
// K5: output = LN( [ctx | ctx2] @ W_fc ). 16 rows/block, grid 512.
__global__ __launch_bounds__(512) void final_kernel(
    const float* __restrict__ ctx, const float* __restrict__ ctx2,
    const float* __restrict__ Wfc, const float* __restrict__ lng,
    const float* __restrict__ lnb, float* __restrict__ out) {
  __shared__ float xs[16][289];
  __shared__ float red[16][4][2];
  const int tid = threadIdx.x;
  const int c = tid & 255;
  const int hf = tid >> 8;
  const int rbase = hf * 8;
  const int lane = tid & 63, wid = (tid >> 6) & 3;
  const int r0 = blockIdx.x * 16;

  for (int e = tid; e < 16 * 288; e += 512) {
    int r = e / 288, i = e - r * 288;
    xs[r][i] = (i < 256) ? ctx[(r0 + r) * 256 + i]
                         : ctx2[(r0 + r) * 32 + (i - 256)];
  }
  __syncthreads();

  float acc[8];
#pragma unroll
  for (int r = 0; r < 8; r++) acc[r] = 0.f;
  for (int i = 0; i < 288; i++) {
    float w = Wfc[i * 256 + c];
#pragma unroll
    for (int r = 0; r < 8; r++) acc[r] += xs[rbase + r][i] * w;
  }

#pragma unroll
  for (int r = 0; r < 8; r++) {
    float s1 = acc[r], s2 = acc[r] * acc[r];
#pragma unroll
    for (int off = 32; off > 0; off >>= 1) {
      s1 += __shfl_xor(s1, off);
      s2 += __shfl_xor(s2, off);
    }
    if (lane == 0) {
      red[rbase + r][wid][0] = s1;
      red[rbase + r][wid][1] = s2;
    }
  }
  __syncthreads();

  float gt = lng[c], bt = lnb[c];
#pragma unroll
  for (int r = 0; r < 8; r++) {
    int row = rbase + r;
    float s1 = red[row][0][0] + red[row][1][0] + red[row][2][0] + red[row][3][0];
    float s2 = red[row][0][1] + red[row][1][1] + red[row][2][1] + red[row][3][1];
    float mu = s1 * (1.f / 256.f);
    float var = s2 * (1.f / 256.f) - mu * mu;
    float inv = rsqrtf(var + 1e-5f);
    out[(r0 + row) * 256 + c] = gt * (acc[r] - mu) * inv + bt;
  }
}

// ---------------------------------------------------------------------------
extern "C" void kernel_launch(void* const* d_in, const int* in_sizes, int n_in,
                              void* d_out, int out_size, void* d_ws,
                              size_t ws_size, hipStream_t stream) {
  const float* inQ = (const float*)d_in[0];
  const float* inK = (const float*)d_in[1];
  const float* inV = (const float*)d_in[2];
  const void* mask = d_in[3];
  const float* matrix = (const float*)d_in[4];
  const float* Wq = (const float*)d_in[5];
  const float* Wk = (const float*)d_in[6];
  const float* Wv = (const float*)d_in[7];
  const float* Wv2 = (const float*)d_in[8];
  const float* Wfc = (const float*)d_in[9];
  const float* lng = (const float*)d_in[10];
  const float* lnb = (const float*)d_in[11];
  const float* fulng = (const float*)d_in[12];
  const float* fulnb = (const float*)d_in[13];
  const float* fuw1 = (const float*)d_in[14];
  const float* fub1 = (const float*)d_in[15];
  const float* fuw2 = (const float*)d_in[16];
  const float* fub2 = (const float*)d_in[17];

  float* ws = (float*)d_ws;
  float* Qp = ws + OFF_QP;
  float* Kt = ws + OFF_KT;
  __hip_bfloat16* Vb = (__hip_bfloat16*)(ws + OFF_VB);
  float* Vp2 = ws + OFF_VP2;
  float* ctx = ws + OFF_CTX;
  float* ctx2 = ws + OFF_CTX2;
  __hip_bfloat16* gws = (__hip_bfloat16*)(ws + OFF_G);
  unsigned int* flag = (unsigned int*)(ws + OFF_FLAG);

  float* out = (float*)d_out;
  float* mout = out + BB * SS * DM;

  hipMemsetAsync(flag, 0, 4, stream);
  mask_or_kernel<<<64, 256, 0, stream>>>((const unsigned int*)mask, flag);
  proj_kernel<<<BB * SS / 16, 512, 0, stream>>>(inQ, inK, inV, Wq, Wk, Wv,
                                                Wv2, Qp, Kt, Vb, Vp2);
  attn_kernel<<<BB * (SS / TQ), 512, 0, stream>>>(
      Qp, Kt, Vb, mask, matrix, fulng, fulnb, fuw1, fub1, fuw2, fub2, ctx,
      gws, flag);
  mout_kernel<<<BB * 64, 256, 0, stream>>>(matrix, gws, mout);
  ctx2_kernel<<<BB * (SS / 16), 256, 0, stream>>>(matrix, Vp2, ctx2);
  final_kernel<<<BB * SS / 16, 512, 0, stream>>>(ctx, ctx2, Wfc, lng, lnb,
                                                 out);
}